// Round 2
// baseline (136.229 us; speedup 1.0000x reference)
//
#include <hip/hip_runtime.h>

#define D_MODEL 256
#define TX 512
#define TM 512
#define NB 2   // x-rows per block in fused kernel

__device__ __forceinline__ float fexp2(float x) { return __builtin_amdgcn_exp2f(x); }
__device__ __forceinline__ float frcp(float x)  { return __builtin_amdgcn_rcpf(x); }

// One kernel, both GEMMs (blockIdx.z selects). C[r][n] = (A[r][:]·W[n][:] + bias[n]) * 2log2e
// M = 2048, N = K = 256. Grid (32, 4, 2), block 256.
__global__ __launch_bounds__(256) void gemm_nt_scale2(
    const float* __restrict__ x,   const float* __restrict__ mem,
    const float* __restrict__ w1,  const float* __restrict__ b1,
    const float* __restrict__ w2,
    float* __restrict__ I1s, float* __restrict__ I2s)
{
    const float C_SCALE = 2.8853900817779268f; // 2*log2(e)
    const float* A;  const float* W;  const float* bias;  float* C;
    if (blockIdx.z == 0) { A = x;   W = w1; bias = b1;      C = I1s; }
    else                 { A = mem; W = w2; bias = nullptr; C = I2s; }

    __shared__ float As[16][68];
    __shared__ float Ws[16][68];
    const int tid = threadIdx.x;
    const int tx = tid & 15, ty = tid >> 4;
    const int rl = tid >> 2, g = tid & 3;
    const int r0 = blockIdx.x * 64, n0 = blockIdx.y * 64;
    float acc[4][4] = {};
    const float* Ap = A + (size_t)(r0 + rl) * 256 + g * 4;
    const float* Wp = W + (size_t)(n0 + rl) * 256 + g * 4;
    for (int k0 = 0; k0 < 256; k0 += 16) {
        float4 a4 = *(const float4*)(Ap + k0);
        float4 w4 = *(const float4*)(Wp + k0);
        __syncthreads();
        As[g*4+0][rl] = a4.x; As[g*4+1][rl] = a4.y;
        As[g*4+2][rl] = a4.z; As[g*4+3][rl] = a4.w;
        Ws[g*4+0][rl] = w4.x; Ws[g*4+1][rl] = w4.y;
        Ws[g*4+2][rl] = w4.z; Ws[g*4+3][rl] = w4.w;
        __syncthreads();
        #pragma unroll
        for (int kk = 0; kk < 16; ++kk) {
            float4 av = *(const float4*)&As[kk][ty*4];
            float4 wv = *(const float4*)&Ws[kk][tx*4];
            float a_[4] = {av.x, av.y, av.z, av.w};
            float w_[4] = {wv.x, wv.y, wv.z, wv.w};
            #pragma unroll
            for (int i = 0; i < 4; ++i)
                #pragma unroll
                for (int j = 0; j < 4; ++j)
                    acc[i][j] = fmaf(a_[i], w_[j], acc[i][j]);
        }
    }
    #pragma unroll
    for (int i = 0; i < 4; ++i) {
        const int r = r0 + ty*4 + i;
        #pragma unroll
        for (int j = 0; j < 4; ++j) {
            const int n = n0 + tx*4 + j;
            float v = acc[i][j];
            if (bias) v += bias[n];
            C[(size_t)r*256 + n] = v * C_SCALE;
        }
    }
}

// Fused: scores = Wsum - 2*sum_d w[d]/(1+exp2(i1s+i2s)), mask, softmax, PV.
// Grid 1024 (= B*TX/NB), block 256 (4 waves).
__global__ __launch_bounds__(256) void fused_tanh_attn(
    const float* __restrict__ I1s,    // [B*TX, D] pre-scaled by 2log2e
    const float* __restrict__ I2s,    // [B*TM, D] pre-scaled
    const float* __restrict__ memory, // [B, TM, D]
    const int*   __restrict__ mask,   // [B, TM]
    const float* __restrict__ wst,    // [D]
    float* __restrict__ out,          // [B*TX, D]
    float* __restrict__ Sout)         // [B*TX, TM]
{
    const float LOG2E = 1.4426950408889634f;
    const int t = threadIdx.x;
    const int blk = blockIdx.x;
    const int b = blk >> 8;                // TX/NB = 256 blocks per batch
    const int x0 = (blk & 255) * NB;
    const int wave = t >> 6, lane = t & 63;

    __shared__ float i1[NB][D_MODEL];      // 2 KB
    __shared__ float wsh[D_MODEL];         // 1 KB
    __shared__ float P[NB][TM];            // 4 KB
    __shared__ float mneg[TM];             // 2 KB
    __shared__ float opart[NB][2][D_MODEL];// 4 KB
    __shared__ float wpart[4];

    // stage I1s rows, wst, mask
    const float* i1g = I1s + ((size_t)b * TX + x0) * D_MODEL;
    #pragma unroll
    for (int x = 0; x < NB; ++x) i1[x][t] = i1g[x * D_MODEL + t];
    const float wv = wst[t];
    wsh[t] = wv;
    mneg[t]       = mask[b*TM + t]       ? 0.f : -__builtin_inff();
    mneg[t + 256] = mask[b*TM + t + 256] ? 0.f : -__builtin_inff();

    // Wsum = sum(wst)
    float s = wv;
    #pragma unroll
    for (int off = 32; off > 0; off >>= 1) s += __shfl_xor(s, off);
    if (lane == 0) wpart[wave] = s;
    __syncthreads();
    const float Wsum = wpart[0] + wpart[1] + wpart[2] + wpart[3];

    // main: thread t owns m = t and m = t+256
    const float* i2a = I2s + ((size_t)b * TM + t) * D_MODEL;
    const float* i2b = i2a + 256 * D_MODEL;

    float acc[NB][2] = {};
    #pragma unroll 2
    for (int d = 0; d < D_MODEL; d += 4) {
        float4 A4 = *(const float4*)(i2a + d);
        float4 B4 = *(const float4*)(i2b + d);
        float4 w4 = *(const float4*)&wsh[d];
        #pragma unroll
        for (int x = 0; x < NB; ++x) {
            float4 i14 = *(const float4*)&i1[x][d];
            acc[x][0] += w4.x * frcp(1.f + fexp2(i14.x + A4.x));
            acc[x][0] += w4.y * frcp(1.f + fexp2(i14.y + A4.y));
            acc[x][0] += w4.z * frcp(1.f + fexp2(i14.z + A4.z));
            acc[x][0] += w4.w * frcp(1.f + fexp2(i14.w + A4.w));
            acc[x][1] += w4.x * frcp(1.f + fexp2(i14.x + B4.x));
            acc[x][1] += w4.y * frcp(1.f + fexp2(i14.y + B4.y));
            acc[x][1] += w4.z * frcp(1.f + fexp2(i14.z + B4.z));
            acc[x][1] += w4.w * frcp(1.f + fexp2(i14.w + B4.w));
        }
    }

    // scores (pre-softmax) with mask
    #pragma unroll
    for (int x = 0; x < NB; ++x) {
        P[x][t]       = Wsum - 2.f * acc[x][0] + mneg[t];
        P[x][t + 256] = Wsum - 2.f * acc[x][1] + mneg[t + 256];
    }
    __syncthreads();

    // softmax: wave 0 -> row 0, wave 1 -> row 1 (8 values per lane)
    if (wave < NB) {
        const int x = wave;
        float4 u0 = *(const float4*)&P[x][lane * 8];
        float4 u1 = *(const float4*)&P[x][lane * 8 + 4];
        float v[8] = {u0.x,u0.y,u0.z,u0.w,u1.x,u1.y,u1.z,u1.w};
        float mx = v[0];
        #pragma unroll
        for (int q = 1; q < 8; ++q) mx = fmaxf(mx, v[q]);
        #pragma unroll
        for (int off = 32; off > 0; off >>= 1) mx = fmaxf(mx, __shfl_xor(mx, off));
        float e[8];
        float sum = 0.f;
        #pragma unroll
        for (int q = 0; q < 8; ++q) { e[q] = fexp2((v[q] - mx) * LOG2E); sum += e[q]; }
        #pragma unroll
        for (int off = 32; off > 0; off >>= 1) sum += __shfl_xor(sum, off);
        const float inv = frcp(sum);
        float4 p0 = {e[0]*inv, e[1]*inv, e[2]*inv, e[3]*inv};
        float4 p1 = {e[4]*inv, e[5]*inv, e[6]*inv, e[7]*inv};
        *(float4*)&P[x][lane*8]   = p0;
        *(float4*)&P[x][lane*8+4] = p1;
        float* Sg = Sout + ((size_t)b*TX + x0 + x) * TM + lane*8;
        *(float4*)Sg     = p0;
        *(float4*)(Sg+4) = p1;
    }
    __syncthreads();

    // PV: wave w -> row (w&1), m-half (w>>1); lane covers d = 4*lane..4*lane+3
    {
        const int row  = wave & 1;
        const int half = wave >> 1;
        const int m0   = half * 256;
        const float* mem = memory + (size_t)b * TM * D_MODEL + (size_t)m0 * D_MODEL + lane * 4;
        float4 o = {0.f, 0.f, 0.f, 0.f};
        #pragma unroll 4
        for (int m = 0; m < 256; ++m) {
            const float p = P[row][m0 + m];
            float4 mv = *(const float4*)(mem + (size_t)m * D_MODEL);
            o.x = fmaf(p, mv.x, o.x);
            o.y = fmaf(p, mv.y, o.y);
            o.z = fmaf(p, mv.z, o.z);
            o.w = fmaf(p, mv.w, o.w);
        }
        *(float4*)&opart[row][half][lane * 4] = o;
    }
    __syncthreads();

    // combine halves: 512 outputs, 2 per thread
    {
        const int row = t >> 7;
        const int d0  = (t & 127) * 2;
        float o0 = opart[row][0][d0]     + opart[row][1][d0];
        float o1 = opart[row][0][d0 + 1] + opart[row][1][d0 + 1];
        float* og = out + ((size_t)b*TX + x0 + row) * D_MODEL + d0;
        og[0] = o0; og[1] = o1;
    }
}

extern "C" void kernel_launch(void* const* d_in, const int* in_sizes, int n_in,
                              void* d_out, int out_size, void* d_ws, size_t ws_size,
                              hipStream_t stream) {
    const float* x    = (const float*)d_in[0];
    const float* mem  = (const float*)d_in[1];
    const int*   mask = (const int*)d_in[2];
    const float* w1   = (const float*)d_in[3];
    const float* b1   = (const float*)d_in[4];
    const float* w2   = (const float*)d_in[5];
    const float* wst  = (const float*)d_in[6];

    float* out  = (float*)d_out;                  // [4*512*256]
    float* Sout = out + 4 * 512 * 256;            // [4*512*512]
    float* I1s  = (float*)d_ws;                   // 524288 floats (2 MB)
    float* I2s  = I1s + 4 * 512 * 256;            // 524288 floats (2 MB)

    dim3 gg(2048 / 64, 256 / 64, 2);
    gemm_nt_scale2<<<gg, 256, 0, stream>>>(x, mem, w1, b1, w2, I1s, I2s);
    fused_tanh_attn<<<1024, 256, 0, stream>>>(I1s, I2s, mem, mask, wst, out, Sout);
}

// Round 3
// 102.858 us; speedup vs baseline: 1.3244x; 1.3244x over previous
//
#include <hip/hip_runtime.h>

#define D_MODEL 256
#define TX 512
#define TM 512
#define NB 2   // x-rows per block in fused kernel

__device__ __forceinline__ float fexp2(float x) { return __builtin_amdgcn_exp2f(x); }
__device__ __forceinline__ float frcp(float x)  { return __builtin_amdgcn_rcpf(x); }

// Two NT-GEMMs in one launch, both scaled by 2*log2(e).
//  z=0: C=I1s  [2048][256] = x   · w1^T + b1   (r0 = bx*64, n0 = by*64, ldc=256)
//  z=1: C=I2sT [256][2048] = w2  · mem^T       (r0 = by*64, n0 = bx*64, ldc=2048)
// Grid (32, 4, 2), block 256.
__global__ __launch_bounds__(256) void gemm_nt_scale2(
    const float* __restrict__ x,   const float* __restrict__ mem,
    const float* __restrict__ w1,  const float* __restrict__ b1,
    const float* __restrict__ w2,
    float* __restrict__ I1s, float* __restrict__ I2sT)
{
    const float C_SCALE = 2.8853900817779268f; // 2*log2(e)
    const float* A; const float* W; const float* bias; float* C;
    int r0, n0, ldc;
    if (blockIdx.z == 0) {
        A = x;  W = w1; bias = b1; C = I1s;
        r0 = blockIdx.x * 64; n0 = blockIdx.y * 64; ldc = 256;
    } else {
        A = w2; W = mem; bias = nullptr; C = I2sT;
        r0 = blockIdx.y * 64; n0 = blockIdx.x * 64; ldc = 2048;
    }

    __shared__ float As[16][68];
    __shared__ float Ws[16][68];
    const int tid = threadIdx.x;
    const int tx = tid & 15, ty = tid >> 4;
    const int rl = tid >> 2, g = tid & 3;
    float acc[4][4] = {};
    const float* Ap = A + (size_t)(r0 + rl) * 256 + g * 4;
    const float* Wp = W + (size_t)(n0 + rl) * 256 + g * 4;
    for (int k0 = 0; k0 < 256; k0 += 16) {
        float4 a4 = *(const float4*)(Ap + k0);
        float4 w4 = *(const float4*)(Wp + k0);
        __syncthreads();
        As[g*4+0][rl] = a4.x; As[g*4+1][rl] = a4.y;
        As[g*4+2][rl] = a4.z; As[g*4+3][rl] = a4.w;
        Ws[g*4+0][rl] = w4.x; Ws[g*4+1][rl] = w4.y;
        Ws[g*4+2][rl] = w4.z; Ws[g*4+3][rl] = w4.w;
        __syncthreads();
        #pragma unroll
        for (int kk = 0; kk < 16; ++kk) {
            float4 av = *(const float4*)&As[kk][ty*4];
            float4 wv = *(const float4*)&Ws[kk][tx*4];
            float a_[4] = {av.x, av.y, av.z, av.w};
            float w_[4] = {wv.x, wv.y, wv.z, wv.w};
            #pragma unroll
            for (int i = 0; i < 4; ++i)
                #pragma unroll
                for (int j = 0; j < 4; ++j)
                    acc[i][j] = fmaf(a_[i], w_[j], acc[i][j]);
        }
    }
    #pragma unroll
    for (int i = 0; i < 4; ++i) {
        const int r = r0 + ty*4 + i;
        #pragma unroll
        for (int j = 0; j < 4; ++j) {
            const int n = n0 + tx*4 + j;
            float v = acc[i][j];
            if (bias) v += bias[n];
            C[(size_t)r*ldc + n] = v * C_SCALE;
        }
    }
}

// Fused: scores = Wsum - 2*sum_d w[d]/(1+exp2(i1s+i2s)), mask, softmax, PV.
// Grid 1024 (= B*TX/NB), block 256 (4 waves). Thread t owns m = 2t, 2t+1.
__global__ __launch_bounds__(256) void fused_tanh_attn(
    const float* __restrict__ I1s,    // [B*TX, D]   pre-scaled by 2log2e
    const float* __restrict__ I2sT,   // [D, B*TM]   pre-scaled, d-major
    const float* __restrict__ memory, // [B, TM, D]
    const int*   __restrict__ mask,   // [B, TM]
    const float* __restrict__ wst,    // [D]
    float* __restrict__ out,          // [B*TX, D]
    float* __restrict__ Sout)         // [B*TX, TM]
{
    const float LOG2E = 1.4426950408889634f;
    const int t = threadIdx.x;
    const int blk = blockIdx.x;
    const int b = blk >> 8;                // 256 blocks per batch
    const int x0 = (blk & 255) * NB;
    const int wave = t >> 6, lane = t & 63;

    __shared__ float i1[NB][D_MODEL];       // 2 KB
    __shared__ float wsh[D_MODEL];          // 1 KB
    __shared__ float P[NB][TM];             // 4 KB
    __shared__ float mneg[TM];              // 2 KB
    __shared__ float opart[NB][2][D_MODEL]; // 4 KB
    __shared__ float wpart[4];

    // stage I1s rows, wst, mask
    const float* i1g = I1s + ((size_t)b * TX + x0) * D_MODEL;
    #pragma unroll
    for (int xx = 0; xx < NB; ++xx) i1[xx][t] = i1g[xx * D_MODEL + t];
    const float wv = wst[t];
    wsh[t] = wv;
    mneg[t]       = mask[b*TM + t]       ? 0.f : -__builtin_inff();
    mneg[t + 256] = mask[b*TM + t + 256] ? 0.f : -__builtin_inff();

    // Wsum = sum(wst)
    float s = wv;
    #pragma unroll
    for (int off = 32; off > 0; off >>= 1) s += __shfl_xor(s, off);
    if (lane == 0) wpart[wave] = s;
    __syncthreads();
    const float Wsum = wpart[0] + wpart[1] + wpart[2] + wpart[3];

    // main loop: coalesced float2 loads from d-major I2sT
    const float* i2p = I2sT + (size_t)b * TM + 2 * t;
    float acc[NB][2] = {};
    #pragma unroll 4
    for (int d = 0; d < D_MODEL; ++d) {
        float2 m2 = *(const float2*)(i2p + (size_t)d * 2048);
        const float w = wsh[d];
        #pragma unroll
        for (int xx = 0; xx < NB; ++xx) {
            const float s1 = i1[xx][d];
            acc[xx][0] += w * frcp(1.f + fexp2(s1 + m2.x));
            acc[xx][1] += w * frcp(1.f + fexp2(s1 + m2.y));
        }
    }

    // scores (pre-softmax) with mask
    #pragma unroll
    for (int xx = 0; xx < NB; ++xx) {
        float2 sc;
        sc.x = Wsum - 2.f * acc[xx][0] + mneg[2*t];
        sc.y = Wsum - 2.f * acc[xx][1] + mneg[2*t + 1];
        *(float2*)&P[xx][2*t] = sc;
    }
    __syncthreads();

    // softmax: wave 0 -> row 0, wave 1 -> row 1 (8 values per lane)
    if (wave < NB) {
        const int xx = wave;
        float4 u0 = *(const float4*)&P[xx][lane * 8];
        float4 u1 = *(const float4*)&P[xx][lane * 8 + 4];
        float v[8] = {u0.x,u0.y,u0.z,u0.w,u1.x,u1.y,u1.z,u1.w};
        float mx = v[0];
        #pragma unroll
        for (int q = 1; q < 8; ++q) mx = fmaxf(mx, v[q]);
        #pragma unroll
        for (int off = 32; off > 0; off >>= 1) mx = fmaxf(mx, __shfl_xor(mx, off));
        float e[8];
        float sum = 0.f;
        #pragma unroll
        for (int q = 0; q < 8; ++q) { e[q] = fexp2((v[q] - mx) * LOG2E); sum += e[q]; }
        #pragma unroll
        for (int off = 32; off > 0; off >>= 1) sum += __shfl_xor(sum, off);
        const float inv = frcp(sum);
        float4 p0 = {e[0]*inv, e[1]*inv, e[2]*inv, e[3]*inv};
        float4 p1 = {e[4]*inv, e[5]*inv, e[6]*inv, e[7]*inv};
        *(float4*)&P[xx][lane*8]   = p0;
        *(float4*)&P[xx][lane*8+4] = p1;
        float* Sg = Sout + ((size_t)b*TX + x0 + xx) * TM + lane*8;
        *(float4*)Sg     = p0;
        *(float4*)(Sg+4) = p1;
    }
    __syncthreads();

    // PV: wave w -> row (w&1), m-half (w>>1); lane covers d = 4*lane..4*lane+3
    {
        const int row  = wave & 1;
        const int half = wave >> 1;
        const int m0   = half * 256;
        const float* mem = memory + (size_t)b * TM * D_MODEL + (size_t)m0 * D_MODEL + lane * 4;
        float4 o = {0.f, 0.f, 0.f, 0.f};
        #pragma unroll 4
        for (int m = 0; m < 256; ++m) {
            const float p = P[row][m0 + m];
            float4 mv = *(const float4*)(mem + (size_t)m * D_MODEL);
            o.x = fmaf(p, mv.x, o.x);
            o.y = fmaf(p, mv.y, o.y);
            o.z = fmaf(p, mv.z, o.z);
            o.w = fmaf(p, mv.w, o.w);
        }
        *(float4*)&opart[row][half][lane * 4] = o;
    }
    __syncthreads();

    // combine halves: 512 outputs, 2 per thread
    {
        const int row = t >> 7;
        const int d0  = (t & 127) * 2;
        float o0 = opart[row][0][d0]     + opart[row][1][d0];
        float o1 = opart[row][0][d0 + 1] + opart[row][1][d0 + 1];
        float* og = out + ((size_t)b*TX + x0 + row) * D_MODEL + d0;
        og[0] = o0; og[1] = o1;
    }
}

extern "C" void kernel_launch(void* const* d_in, const int* in_sizes, int n_in,
                              void* d_out, int out_size, void* d_ws, size_t ws_size,
                              hipStream_t stream) {
    const float* x    = (const float*)d_in[0];
    const float* mem  = (const float*)d_in[1];
    const int*   mask = (const int*)d_in[2];
    const float* w1   = (const float*)d_in[3];
    const float* b1   = (const float*)d_in[4];
    const float* w2   = (const float*)d_in[5];
    const float* wst  = (const float*)d_in[6];

    float* out  = (float*)d_out;                  // [4*512*256]
    float* Sout = out + 4 * 512 * 256;            // [4*512*512]
    float* I1s  = (float*)d_ws;                   // 524288 floats (2 MB), [2048][256]
    float* I2sT = I1s + 4 * 512 * 256;            // 524288 floats (2 MB), [256][2048]

    dim3 gg(32, 4, 2);
    gemm_nt_scale2<<<gg, 256, 0, stream>>>(x, mem, w1, b1, w2, I1s, I2sT);
    fused_tanh_attn<<<1024, 256, 0, stream>>>(I1s, I2sT, mem, mask, wst, out, Sout);
}

// Round 4
// 76.275 us; speedup vs baseline: 1.7860x; 1.3485x over previous
//
#include <hip/hip_runtime.h>

#define D_MODEL 256
#define TX 512
#define TM 512

__device__ __forceinline__ float fexp2(float x) { return __builtin_amdgcn_exp2f(x); }
__device__ __forceinline__ float frcp(float x)  { return __builtin_amdgcn_rcpf(x); }

// Two NT-GEMMs in one launch; epilogues write exp2(2log2e * value):
//  z=0: E1 [2048][256] = exp2(c*(x · w1^T + b1))           row-major
//  z=1: E2p packed     = exp2(c*(w2 · mem^T))  at [(d>>2)*8192 + gm*4 + (d&3)]
//       (gm = global m index b*512+m; 4 consecutive d packed per m)
// Grid (32, 4, 2), block 256.
__global__ __launch_bounds__(256) void gemm_exp2(
    const float* __restrict__ x,   const float* __restrict__ mem,
    const float* __restrict__ w1,  const float* __restrict__ b1,
    const float* __restrict__ w2,
    float* __restrict__ E1, float* __restrict__ E2p)
{
    const float C_SCALE = 2.8853900817779268f; // 2*log2(e)
    const float* A; const float* W;
    int r0, n0;
    if (blockIdx.z == 0) { A = x;  W = w1; r0 = blockIdx.x * 64; n0 = blockIdx.y * 64; }
    else                 { A = w2; W = mem; r0 = blockIdx.y * 64; n0 = blockIdx.x * 64; }

    __shared__ float As[16][68];
    __shared__ float Ws[16][68];
    const int tid = threadIdx.x;
    const int tx = tid & 15, ty = tid >> 4;
    const int rl = tid >> 2, g = tid & 3;
    float acc[4][4] = {};
    const float* Ap = A + (size_t)(r0 + rl) * 256 + g * 4;
    const float* Wp = W + (size_t)(n0 + rl) * 256 + g * 4;
    for (int k0 = 0; k0 < 256; k0 += 16) {
        float4 a4 = *(const float4*)(Ap + k0);
        float4 w4 = *(const float4*)(Wp + k0);
        __syncthreads();
        As[g*4+0][rl] = a4.x; As[g*4+1][rl] = a4.y;
        As[g*4+2][rl] = a4.z; As[g*4+3][rl] = a4.w;
        Ws[g*4+0][rl] = w4.x; Ws[g*4+1][rl] = w4.y;
        Ws[g*4+2][rl] = w4.z; Ws[g*4+3][rl] = w4.w;
        __syncthreads();
        #pragma unroll
        for (int kk = 0; kk < 16; ++kk) {
            float4 av = *(const float4*)&As[kk][ty*4];
            float4 wv = *(const float4*)&Ws[kk][tx*4];
            float a_[4] = {av.x, av.y, av.z, av.w};
            float w_[4] = {wv.x, wv.y, wv.z, wv.w};
            #pragma unroll
            for (int i = 0; i < 4; ++i)
                #pragma unroll
                for (int j = 0; j < 4; ++j)
                    acc[i][j] = fmaf(a_[i], w_[j], acc[i][j]);
        }
    }
    if (blockIdx.z == 0) {
        #pragma unroll
        for (int i = 0; i < 4; ++i) {
            const int r = r0 + ty*4 + i;
            #pragma unroll
            for (int j = 0; j < 4; ++j) {
                const int n = n0 + tx*4 + j;
                E1[(size_t)r*256 + n] = fexp2(C_SCALE * (acc[i][j] + b1[n]));
            }
        }
    } else {
        #pragma unroll
        for (int i = 0; i < 4; ++i) {
            const int r = r0 + ty*4 + i;   // d index
            #pragma unroll
            for (int j = 0; j < 4; ++j) {
                const int n = n0 + tx*4 + j;  // gm index
                E2p[(size_t)(r >> 2)*8192 + (size_t)n*4 + (r & 3)] = fexp2(C_SCALE * acc[i][j]);
            }
        }
    }
}

// Fused: S = Wsum - 2*sum_d w[d]*rcp(1 + E1*E2), mask, softmax, PV.
// Grid 512 (= B*TX/4), block 512 (8 waves). Block owns 4 x-rows; thread t owns m = t.
__global__ __launch_bounds__(512) void fused_tanh_attn(
    const float* __restrict__ E1,     // [B*TX, D]
    const float* __restrict__ E2p,    // packed [(d>>2)][gm][4]
    const float* __restrict__ memory, // [B, TM, D]
    const int*   __restrict__ mask,   // [B, TM]
    const float* __restrict__ wst,    // [D]
    float* __restrict__ out,          // [B*TX, D]
    float* __restrict__ Sout)         // [B*TX, TM]
{
    const float LOG2E = 1.4426950408889634f;
    const int t = threadIdx.x;
    const int blk = blockIdx.x;
    const int b = blk >> 7;                // 128 blocks per batch
    const int x0 = (blk & 127) * 4;
    const int wave = t >> 6, lane = t & 63;

    __shared__ float i1T[D_MODEL][4];        // 4 KB  (E1 transposed: [d][row])
    __shared__ float wsh[D_MODEL];           // 1 KB
    __shared__ float P[4][TM];               // 8 KB
    __shared__ float mneg[TM];               // 2 KB
    __shared__ float opart[4][2][D_MODEL];   // 8 KB
    __shared__ float wpart[8];

    // stage E1 rows transposed, wst, mask
    {
        const float* i1g = E1 + ((size_t)b * TX + x0) * D_MODEL;
        const int row = t >> 8, col = t & 255;
        i1T[col][row]     = i1g[(size_t)row * D_MODEL + col];
        i1T[col][row + 2] = i1g[(size_t)(row + 2) * D_MODEL + col];
    }
    if (t < 256) wsh[t] = wst[t];
    mneg[t] = mask[b*TM + t] ? 0.f : -__builtin_inff();

    // Wsum = sum(wst)
    {
        float s = (t < 256) ? wst[t] : 0.f;
        #pragma unroll
        for (int off = 32; off > 0; off >>= 1) s += __shfl_xor(s, off);
        if (lane == 0) wpart[wave] = s;
    }

    // first E2 group load (global; before the LDS barrier is fine)
    const float* e2ptr = E2p + ((size_t)b * TM + t) * 4;
    float4 e2 = *(const float4*)e2ptr;

    __syncthreads();
    const float Wsum = wpart[0] + wpart[1] + wpart[2] + wpart[3]
                     + wpart[4] + wpart[5] + wpart[6] + wpart[7];

    // main loop: 64 groups of 4 d; 1-deep prefetch of the next float4
    float acc0 = 0.f, acc1 = 0.f, acc2 = 0.f, acc3 = 0.f;
    for (int gg = 0; gg < 64; ++gg) {
        float4 e2n = e2;
        if (gg < 63) e2n = *(const float4*)(e2ptr + (size_t)(gg + 1) * 8192);
        float4 w4 = *(const float4*)&wsh[gg * 4];
        const float wv_[4] = {w4.x, w4.y, w4.z, w4.w};
        const float e2_[4] = {e2.x, e2.y, e2.z, e2.w};
        #pragma unroll
        for (int ds = 0; ds < 4; ++ds) {
            float4 e1 = *(const float4*)&i1T[gg * 4 + ds][0];
            const float ev = e2_[ds];
            const float w  = wv_[ds];
            acc0 = fmaf(w, frcp(fmaf(e1.x, ev, 1.f)), acc0);
            acc1 = fmaf(w, frcp(fmaf(e1.y, ev, 1.f)), acc1);
            acc2 = fmaf(w, frcp(fmaf(e1.z, ev, 1.f)), acc2);
            acc3 = fmaf(w, frcp(fmaf(e1.w, ev, 1.f)), acc3);
        }
        e2 = e2n;
    }

    // scores with mask
    {
        const float mn = mneg[t];
        P[0][t] = Wsum - 2.f * acc0 + mn;
        P[1][t] = Wsum - 2.f * acc1 + mn;
        P[2][t] = Wsum - 2.f * acc2 + mn;
        P[3][t] = Wsum - 2.f * acc3 + mn;
    }
    __syncthreads();

    // softmax: waves 0..3 -> rows 0..3 (8 values per lane)
    if (wave < 4) {
        const int xx = wave;
        float4 u0 = *(const float4*)&P[xx][lane * 8];
        float4 u1 = *(const float4*)&P[xx][lane * 8 + 4];
        float v[8] = {u0.x,u0.y,u0.z,u0.w,u1.x,u1.y,u1.z,u1.w};
        float mx = v[0];
        #pragma unroll
        for (int q = 1; q < 8; ++q) mx = fmaxf(mx, v[q]);
        #pragma unroll
        for (int off = 32; off > 0; off >>= 1) mx = fmaxf(mx, __shfl_xor(mx, off));
        float e[8];
        float sum = 0.f;
        #pragma unroll
        for (int q = 0; q < 8; ++q) { e[q] = fexp2((v[q] - mx) * LOG2E); sum += e[q]; }
        #pragma unroll
        for (int off = 32; off > 0; off >>= 1) sum += __shfl_xor(sum, off);
        const float inv = frcp(sum);
        float4 p0 = {e[0]*inv, e[1]*inv, e[2]*inv, e[3]*inv};
        float4 p1 = {e[4]*inv, e[5]*inv, e[6]*inv, e[7]*inv};
        *(float4*)&P[xx][lane*8]   = p0;
        *(float4*)&P[xx][lane*8+4] = p1;
        float* Sg = Sout + ((size_t)b*TX + x0 + xx) * TM + lane*8;
        *(float4*)Sg     = p0;
        *(float4*)(Sg+4) = p1;
    }
    __syncthreads();

    // PV: wave w -> row (w>>1), m-half (w&1); lane covers d = 4*lane..4*lane+3
    {
        const int row  = wave >> 1;
        const int half = wave & 1;
        const int m0   = half * 256;
        const float* mem = memory + (size_t)b * TM * D_MODEL + (size_t)m0 * D_MODEL + lane * 4;
        float4 o = {0.f, 0.f, 0.f, 0.f};
        #pragma unroll 4
        for (int m = 0; m < 256; ++m) {
            const float p = P[row][m0 + m];
            float4 mv = *(const float4*)(mem + (size_t)m * D_MODEL);
            o.x = fmaf(p, mv.x, o.x);
            o.y = fmaf(p, mv.y, o.y);
            o.z = fmaf(p, mv.z, o.z);
            o.w = fmaf(p, mv.w, o.w);
        }
        *(float4*)&opart[row][half][lane * 4] = o;
    }
    __syncthreads();

    // combine halves: 1024 outputs, 2 per thread
    {
        const int row = t >> 7;
        const int d0  = (t & 127) * 2;
        float o0 = opart[row][0][d0]     + opart[row][1][d0];
        float o1 = opart[row][0][d0 + 1] + opart[row][1][d0 + 1];
        float* og = out + ((size_t)b*TX + x0 + row) * D_MODEL + d0;
        og[0] = o0; og[1] = o1;
    }
}

extern "C" void kernel_launch(void* const* d_in, const int* in_sizes, int n_in,
                              void* d_out, int out_size, void* d_ws, size_t ws_size,
                              hipStream_t stream) {
    const float* x    = (const float*)d_in[0];
    const float* mem  = (const float*)d_in[1];
    const int*   mask = (const int*)d_in[2];
    const float* w1   = (const float*)d_in[3];
    const float* b1   = (const float*)d_in[4];
    const float* w2   = (const float*)d_in[5];
    const float* wst  = (const float*)d_in[6];

    float* out  = (float*)d_out;                  // [4*512*256]
    float* Sout = out + 4 * 512 * 256;            // [4*512*512]
    float* E1   = (float*)d_ws;                   // 524288 floats (2 MB), [2048][256]
    float* E2p  = E1 + 4 * 512 * 256;             // 524288 floats (2 MB), packed

    dim3 gg(32, 4, 2);
    gemm_exp2<<<gg, 256, 0, stream>>>(x, mem, w1, b1, w2, E1, E2p);
    fused_tanh_attn<<<512, 512, 0, stream>>>(E1, E2p, mem, mask, wst, out, Sout);
}